// Round 10
// baseline (2491.196 us; speedup 1.0000x reference)
//
#include <hip/hip_runtime.h>
#include <stdint.h>

typedef __attribute__((ext_vector_type(8))) short bf16x8;
typedef __attribute__((ext_vector_type(16))) float f32x16;
typedef __attribute__((ext_vector_type(4))) unsigned int u32x4;

__device__ __forceinline__ unsigned short f2bf(float f) {
  unsigned int u = __float_as_uint(f);
  return (unsigned short)((u + 0x7fffu + ((u >> 16) & 1u)) >> 16);  // RNE
}

__device__ __forceinline__ void gload16(const void* g, void* l) {
  __builtin_amdgcn_global_load_lds((const __attribute__((address_space(1))) void*)g,
                                   (__attribute__((address_space(3))) void*)l, 16, 0, 0);
}

// ---------------------------------------------------------------- zero
__global__ void zero_k(u32x4* __restrict__ p, int n16) {
  int i = blockIdx.x * blockDim.x + threadIdx.x;
  int stride = gridDim.x * blockDim.x;
  u32x4 z = {0u, 0u, 0u, 0u};
  for (; i < n16; i += stride) p[i] = z;
}

// ------------------------------------------- fp32 NHWC -> padded bf16 NHWC
__global__ void conv_in_k(const float* __restrict__ x, unsigned short* __restrict__ dst,
                          int H, int total) {
  int idx = blockIdx.x * 256 + threadIdx.x;
  if (idx >= total) return;
  const int W = H, Hp = H + 2, Wp = H + 2;
  int c8 = idx & 31;
  int rest = idx >> 5;
  int xp = rest % Wp;
  int r2 = rest / Wp;
  int yp = r2 % Hp;
  int n = r2 / Hp;
  u32x4 o = {0u, 0u, 0u, 0u};
  int iy = yp - 1, ix = xp - 1;
  if ((unsigned)iy < (unsigned)H && (unsigned)ix < (unsigned)W) {
    const float* s = x + ((long)((n * H + iy) * W + ix) * 256 + c8 * 8);
    float4 a = *(const float4*)s;
    float4 b = *(const float4*)(s + 4);
    o.x = f2bf(a.x) | ((unsigned)f2bf(a.y) << 16);
    o.y = f2bf(a.z) | ((unsigned)f2bf(a.w) << 16);
    o.z = f2bf(b.x) | ((unsigned)f2bf(b.y) << 16);
    o.w = f2bf(b.z) | ((unsigned)f2bf(b.w) << 16);
  }
  *(u32x4*)(dst + (long)idx * 8) = o;
}

// -------- HWIO fp32 -> bf16 32x32x16-fragment layout
// chunk = (stage*4 + kstep)*NB32 + jg ; lane l: col = jg*32 + (l&31),
// k = stage*64 + kstep*16 + (l>>5)*8 + e  (stage = tap*4+cc)
__global__ void conv_w_k(const float* __restrict__ w, unsigned short* __restrict__ wTf,
                         int CoutReal, int NB32, int totalThreads) {
  int idx = blockIdx.x * 256 + threadIdx.x;
  if (idx >= totalThreads) return;
  int l = idx & 63;
  int chunk = idx >> 6;
  int jg = chunk % NB32;
  int rest = chunk / NB32;
  int kstep = rest & 3;
  int stage = rest >> 2;
  int col = jg * 32 + (l & 31);
  int kbase = stage * 64 + kstep * 16 + ((l >> 5) << 3);
  u32x4 o = {0u, 0u, 0u, 0u};
  if (col < CoutReal) {
    unsigned short v[8];
#pragma unroll
    for (int e = 0; e < 8; ++e)
      v[e] = f2bf(w[(long)(kbase + e) * CoutReal + col]);
    o.x = v[0] | ((unsigned)v[1] << 16);
    o.y = v[2] | ((unsigned)v[3] << 16);
    o.z = v[4] | ((unsigned)v[5] << 16);
    o.w = v[6] | ((unsigned)v[7] << 16);
  }
  *(u32x4*)(wTf + (long)idx * 8) = o;
}

// ---------------------------------------------------------------- conv 3x3
// 32x32x16 MFMA version. Tile = 8x16 px (128) x NJ*64 couts. 4 waves:
// wave = 64 px (2 frags of 32) x NJ*32 co. acc[2][NJ] f32x16 = 64 VGPR (NJ=2).
// A: T14 double-buffered LDS halo, source-side XOR swizzle. A frag: lane row
// = l&31, k = (l>>5)*8 (ds_read_b128 per kstep). B ring-2 from L2. T5 setprio.
template<int NJ, bool FINAL>
__global__ __launch_bounds__(256, 2)
void conv3x3_k(const unsigned short* __restrict__ src,
               const unsigned short* __restrict__ wTf,
               const float* __restrict__ bias,
               unsigned short* __restrict__ dstAct,
               float* __restrict__ dstOut,
               int H, int lntx, int lnty, int CoutReal, int NB32)
{
  __shared__ char smem[49152];   // A dbuf: 2 x 24576; epilogue reuses [0,32768)
  const int tid = threadIdx.x;
  const int W = H, Hp = H + 2, RL = H + 2;
  const int np = gridDim.x;
  const int bx = blockIdx.x;
  const int t = (bx & 7) * (np >> 3) + (bx >> 3);      // XCD-chunked swizzle
  const int tx = (t & ((1 << lntx) - 1)) << 4;
  const int ty = ((t >> lntx) & ((1 << lnty) - 1)) << 3;
  const int n_img = t >> (lntx + lnty);
  const int tileN = blockIdx.y * (NJ * 64);

  // A staging: 180 halo rows (10y x 18x) x 128 B = 1440 chunks; 6 x 256 thr
  int srcOff[6];
#pragma unroll
  for (int j = 0; j < 6; ++j) {
    int q = j * 256 + tid;
    int hr = q >> 3, c = q & 7;
    if (hr >= 180) hr = 0;                 // tail dup, harmless
    int hy = hr / 18, hx = hr - hy * 18;
    int lch = c ^ (hr & 7);                // inverse swizzle on global source
    srcOff[j] = ((n_img * Hp + ty + hy) * RL + tx + hx) * 256 + lch * 8;
  }

  const int lane = tid & 63;
  const int wv = tid >> 6;
  const int l31 = lane & 31;
  const int kh = lane >> 5;                // k-half within fragment
  const int pxW = (wv & 1) * 64;
  const int jgW = (tileN >> 5) + (wv >> 1) * NJ;
  const unsigned short* wBp = wTf + (size_t)jgW * 512 + lane * 8;
  const size_t stageStride = (size_t)NB32 << 11;     // elems per stage

  int rBase[2];
#pragma unroll
  for (int m = 0; m < 2; ++m) {
    const int px = pxW + m * 32 + l31;
    rBase[m] = (px >> 4) * 18 + (px & 15);
  }

  f32x16 acc[2][NJ];
#pragma unroll
  for (int m = 0; m < 2; ++m)
#pragma unroll
    for (int n = 0; n < NJ; ++n)
      acc[m][n] = (f32x16){0.f};

  auto loadB = [&](bf16x8 (&dst)[NJ][4], int stage) {
    const unsigned short* bp = wBp + stage * stageStride;
#pragma unroll
    for (int jf = 0; jf < NJ; ++jf)
#pragma unroll
      for (int ks = 0; ks < 4; ++ks)
        dst[jf][ks] = *(const bf16x8*)(bp + (ks * NB32 + jf) * 512);
  };
  auto loadAm = [&](bf16x8 (&dst)[4], const char* buf, int tap, int m) {
    const int ky = tap / 3, kx = tap - ky * 3;
    const int rA = rBase[m] + ky * 18 + kx;
    const char* rb = buf + rA * 128;
    const int sw = rA & 7;
#pragma unroll
    for (int ks = 0; ks < 4; ++ks)
      dst[ks] = *(const bf16x8*)(rb + (((ks * 2 + kh) ^ sw) << 4));
  };

  bf16x8 avr[2][4];                        // A fragments, in-place rotated
  bf16x8 bb[2][NJ][4];                     // B static ring-2
  loadB(bb[0], 0);                         // stage (tap0, cc0)

  // prologue: stage cc=0 into buf0
#pragma unroll
  for (int j = 0; j < 6; ++j)
    gload16(src + srcOff[j], smem + j * 4096 + tid * 16);
  __syncthreads();
#pragma unroll
  for (int m = 0; m < 2; ++m)
    loadAm(avr[m], smem, 0, m);

#pragma unroll
  for (int cc = 0; cc < 4; ++cc) {
    char* cbuf = smem + (cc & 1) * 24576;
    if (cc < 3) {                          // issue next A slice early (T14)
      char* nbuf = smem + ((cc + 1) & 1) * 24576;
#pragma unroll
      for (int j = 0; j < 6; ++j)
        gload16(src + srcOff[j] + (cc + 1) * 64, nbuf + j * 4096 + tid * 16);
    }
#pragma unroll
    for (int tap = 0; tap < 9; ++tap) {
      const int s = cc * 9 + tap;          // static ring parity for B
      const int cur = s & 1, nxt = cur ^ 1;
      if (cc < 3 || tap < 8)
        loadB(bb[nxt], (tap < 8) ? ((tap + 1) * 4 + cc) : (cc + 1));
      __builtin_amdgcn_s_setprio(1);       // T5
#pragma unroll
      for (int m = 0; m < 2; ++m) {
#pragma unroll
        for (int ks = 0; ks < 4; ++ks)
#pragma unroll
          for (int jf = 0; jf < NJ; ++jf)
            acc[m][jf] = __builtin_amdgcn_mfma_f32_32x32x16_bf16(
                avr[m][ks], bb[cur][jf][ks], acc[m][jf], 0, 0, 0);
        if (tap < 8)
          loadAm(avr[m], cbuf, tap + 1, m);   // in-place rotate
      }
      __builtin_amdgcn_s_setprio(0);
    }
    __syncthreads();                       // drains vmcnt: next buf ready
    if (cc < 3) {                          // av tap0 of next cc (post-barrier)
      const char* nbuf = smem + ((cc + 1) & 1) * 24576;
#pragma unroll
      for (int m = 0; m < 2; ++m)
        loadAm(avr[m], nbuf, 0, m);
    }
  }

  // ---- epilogue. C/D 32x32 frag (verified m74/m101): col = lane&31,
  // row-in-frag = (reg&3) + 8*(reg>>2) + 4*(lane>>5).
  if constexpr (FINAL) {
    constexpr int NCOL = NJ * 64;
    constexpr int MASK = NCOL / 4 - 1;
    float* cf = (float*)smem;              // [64 px][NCOL co] fp32 per half
#pragma unroll
    for (int h = 0; h < 2; ++h) {
      if (h) __syncthreads();
      if ((wv & 1) == h) {
#pragma unroll
        for (int jf = 0; jf < NJ; ++jf) {
          const int col = (wv >> 1) * (NJ * 32) + jf * 32 + l31;
          const int colG = tileN + col;
          const float bvl = (colG < CoutReal) ? bias[colG] : 0.f;
          const int c32 = col >> 2;
#pragma unroll
          for (int m = 0; m < 2; ++m)
#pragma unroll
            for (int reg = 0; reg < 16; ++reg) {
              const int pxl = m * 32 + (reg & 3) + 8 * (reg >> 2) + 4 * kh;
              const int phys = (c32 + ((pxl >> 2) & 1) * 4) & MASK;
              cf[pxl * NCOL + phys * 4 + (col & 3)] = acc[m][jf][reg] + bvl;
            }
        }
      }
      __syncthreads();
#pragma unroll
      for (int it = 0; it < NCOL / 16; ++it) {
        const int q = it * 256 + tid;
        const int pxl = q / (NCOL / 4), c32 = q & MASK;
        const int colG = tileN + c32 * 4;
        if (colG < CoutReal) {
          const int phys = (c32 + ((pxl >> 2) & 1) * 4) & MASK;
          u32x4 v = *(const u32x4*)(cf + pxl * NCOL + phys * 4);
          const int px = h * 64 + pxl;
          const int y = ty + (px >> 4), x = tx + (px & 15);
          const size_t p = ((size_t)(n_img * H + y)) * W + x;
          *(u32x4*)(dstOut + p * CoutReal + colG) = v;
        }
      }
    }
  } else {
    __syncthreads();                       // smem free; reuse as C tile
    unsigned short* cb = (unsigned short*)smem;   // [128 px][128 co] bf16 = 32 KB
#pragma unroll
    for (int jf = 0; jf < NJ; ++jf) {
      const int col = (wv >> 1) * (NJ * 32) + jf * 32 + l31;
      const float bvl = bias[tileN + col];
      const int c16 = col >> 3;
#pragma unroll
      for (int m = 0; m < 2; ++m)
#pragma unroll
        for (int reg = 0; reg < 16; ++reg) {
          const int px = pxW + m * 32 + (reg & 3) + 8 * (reg >> 2) + 4 * kh;
          const int phys = (c16 + ((px >> 2) & 3) * 2) & 15;
          cb[(px & 127) * 128 + phys * 8 + (col & 7)] =
              f2bf(fmaxf(acc[m][jf][reg] + bvl, 0.f));
        }
    }
    __syncthreads();
#pragma unroll
    for (int it = 0; it < 8; ++it) {
      const int q = it * 256 + tid;
      const int px = q >> 4, c16 = q & 15;
      const int phys = (c16 + ((px >> 2) & 3) * 2) & 15;
      u32x4 v = *(const u32x4*)(cb + px * 128 + phys * 8);
      const int y = ty + (px >> 4), x = tx + (px & 15);
      const size_t o = ((size_t)(n_img * Hp + y + 1) * RL + x + 1) * 256 + tileN + c16 * 8;
      *(u32x4*)(dstAct + o) = v;
    }
  }
}

// ---------------------------------------------------------------- host
static void run_branch(const unsigned short* A, unsigned short* Am, unsigned short* B,
                       const unsigned short* wT, const float* bias,
                       const unsigned short* wTout, const float* biasOut,
                       bool cls, float* out, int H, int lntx, int lnty,
                       hipStream_t stream) {
  dim3 blk(256);
  const int np = 8 * (H / 16) * (H / 8);
  dim3 g1(np, 2);
  conv3x3_k<2, false><<<g1, blk, 0, stream>>>(A,  wT + 0L * 589824, bias + 0,   B,  nullptr, H, lntx, lnty, 256, 8);
  conv3x3_k<2, false><<<g1, blk, 0, stream>>>(B,  wT + 1L * 589824, bias + 256, Am, nullptr, H, lntx, lnty, 256, 8);
  conv3x3_k<2, false><<<g1, blk, 0, stream>>>(Am, wT + 2L * 589824, bias + 512, B,  nullptr, H, lntx, lnty, 256, 8);
  conv3x3_k<2, false><<<g1, blk, 0, stream>>>(B,  wT + 3L * 589824, bias + 768, Am, nullptr, H, lntx, lnty, 256, 8);
  if (cls) {
    dim3 g2(np, 6);
    conv3x3_k<2, true><<<g2, blk, 0, stream>>>(Am, wTout, biasOut, nullptr, out, H, lntx, lnty, 720, 24);
  } else {
    dim3 g2(np, 1);
    conv3x3_k<1, true><<<g2, blk, 0, stream>>>(Am, wTout, biasOut, nullptr, out, H, lntx, lnty, 36, 2);
  }
}

extern "C" void kernel_launch(void* const* d_in, const int* in_sizes, int n_in,
                              void* d_out, int out_size, void* d_ws, size_t ws_size,
                              hipStream_t stream) {
  const float* x[3] = {(const float*)d_in[0], (const float*)d_in[1], (const float*)d_in[2]};
  const float* cls_w      = (const float*)d_in[3];
  const float* cls_b      = (const float*)d_in[4];
  const float* bbox_w     = (const float*)d_in[5];
  const float* bbox_b     = (const float*)d_in[6];
  const float* cls_out_w  = (const float*)d_in[7];
  const float* cls_out_b  = (const float*)d_in[8];
  const float* bbox_out_w = (const float*)d_in[9];
  const float* bbox_out_b = (const float*)d_in[10];
  float* out = (float*)d_out;

  char* ws = (char*)d_ws;
  unsigned short* bufA = (unsigned short*)ws;
  unsigned short* bufB = (unsigned short*)(ws + 69222400);
  unsigned short* wt   = (unsigned short*)(ws + 138444800);
  unsigned short* wT_cls      = wt;
  unsigned short* wT_bbox     = wt + 4L * 589824;
  unsigned short* wT_cls_out  = wt + 8L * 589824;         // 36*4*24*512 = 1769472
  unsigned short* wT_bbox_out = wT_cls_out + 2211840;     // 36*4*2*512 = 147456

  for (int i = 0; i < 4; ++i) {
    conv_w_k<<<288, 256, 0, stream>>>(cls_w  + (long)i * 589824, wT_cls  + (long)i * 589824, 256, 8, 73728);
    conv_w_k<<<288, 256, 0, stream>>>(bbox_w + (long)i * 589824, wT_bbox + (long)i * 589824, 256, 8, 73728);
  }
  conv_w_k<<<864, 256, 0, stream>>>(cls_out_w,  wT_cls_out,  720, 24, 221184);
  conv_w_k<<<72, 256, 0, stream>>>(bbox_out_w, wT_bbox_out, 36, 2, 18432);

  const long clsOff[3] = {0L, 94371840L, 117964800L};
  const long boxOff[3] = {123863040L, 128581632L, 129761280L};
  const int Hs[3]    = {128, 64, 32};
  const int lntxs[3] = {3, 2, 1};
  const int lntys[3] = {4, 3, 2};

  for (int lv = 0; lv < 3; ++lv) {
    const int H = Hs[lv], Hp = H + 2;
    const int paddedElems = 8 * Hp * Hp * 256;
    const int totalConv = 8 * Hp * Hp * 32;

    zero_k<<<2048, 256, 0, stream>>>((u32x4*)bufB, paddedElems / 8);

    conv_in_k<<<(totalConv + 255) / 256, 256, 0, stream>>>(x[lv], bufA, H, totalConv);
    run_branch(bufA, bufA, bufB, wT_cls, cls_b, wT_cls_out, cls_out_b,
               true, out + clsOff[lv], H, lntxs[lv], lntys[lv], stream);

    conv_in_k<<<(totalConv + 255) / 256, 256, 0, stream>>>(x[lv], bufA, H, totalConv);
    run_branch(bufA, bufA, bufB, wT_bbox, bbox_b, wT_bbox_out, bbox_out_b,
               false, out + boxOff[lv], H, lntxs[lv], lntys[lv], stream);
  }
}